// Round 11
// baseline (461.171 us; speedup 1.0000x reference)
//
#include <hip/hip_runtime.h>
#include <stdint.h>

typedef unsigned short u16;
typedef __attribute__((ext_vector_type(8))) short short8;   // 8 bf16 = 4 VGPRs
typedef __attribute__((ext_vector_type(4))) float floatx4;  // MFMA accumulator

#define NTOK 4096
#define DDIM 1024
#define FDIM 2048
#define NEXP 8

__device__ __forceinline__ u16 f2bf(float f) {
    union { float f; uint32_t u; } v; v.f = f;
    uint32_t r = v.u + 0x7fff + ((v.u >> 16) & 1);  // RNE
    return (u16)(r >> 16);
}
__device__ __forceinline__ uint32_t pk2(float a, float b) {
    return (uint32_t)f2bf(a) | ((uint32_t)f2bf(b) << 16);
}
// async global->LDS, 16B per lane; LDS dest is wave-uniform base + lane*16
__device__ __forceinline__ void gl_lds16(const u16* g, u16* l) {
    __builtin_amdgcn_global_load_lds(
        (const __attribute__((address_space(1))) uint32_t*)g,
        (__attribute__((address_space(3))) uint32_t*)l, 16, 0, 0);
}

// pipeline sync (round-7-verified skeleton, now with a 256-tile to give the
// waits real compute cover):
#define WAITV0 asm volatile("s_waitcnt vmcnt(0)" ::: "memory")
#define LGKM0  asm volatile("s_waitcnt lgkmcnt(0)" ::: "memory")
#define BAR    __builtin_amdgcn_s_barrier()
#define CFENCE asm volatile("" ::: "memory")

// ---------------------------------------------------------------- router (+ x->bf16 fused)
__global__ __launch_bounds__(256)
void router_kernel(const float* __restrict__ x, const float* __restrict__ rw,
                   int* __restrict__ topk_e, float* __restrict__ topk_w,
                   u16* __restrict__ xb) {
    const int lane = threadIdx.x & 63;
    const int wv = threadIdx.x >> 6;
    const int tok = blockIdx.x * 4 + wv;
    const float* xr = x + (size_t)tok * DDIM;
    u16* xo = xb + (size_t)tok * DDIM;
    float acc[8];
#pragma unroll
    for (int e = 0; e < 8; ++e) acc[e] = 0.f;
#pragma unroll
    for (int it = 0; it < 4; ++it) {
        int d0 = (it * 64 + lane) * 4;
        float4 xv = *(const float4*)(xr + d0);
        uint2 o = { pk2(xv.x, xv.y), pk2(xv.z, xv.w) };
        *(uint2*)(xo + d0) = o;   // fused bf16 conversion
#pragma unroll
        for (int e = 0; e < 8; ++e) {
            float4 wv4 = *(const float4*)(rw + (size_t)e * DDIM + d0);
            acc[e] += xv.x * wv4.x + xv.y * wv4.y + xv.z * wv4.z + xv.w * wv4.w;
        }
    }
#pragma unroll
    for (int s = 32; s > 0; s >>= 1)
#pragma unroll
        for (int e = 0; e < 8; ++e) acc[e] += __shfl_down(acc[e], s);
    if (lane == 0) {
        int e0 = 0;
#pragma unroll
        for (int e = 1; e < 8; ++e) if (acc[e] > acc[e0]) e0 = e;
        int e1 = (e0 == 0) ? 1 : 0;
#pragma unroll
        for (int e = 0; e < 8; ++e) if (e != e0 && acc[e] > acc[e1]) e1 = e;
        float w0 = 1.f / (1.f + __expf(acc[e1] - acc[e0]));
        topk_e[tok * 2 + 0] = e0;
        topk_e[tok * 2 + 1] = e1;
        topk_w[tok * 2 + 0] = w0;
        topk_w[tok * 2 + 1] = 1.f - w0;
    }
}

// ---------------------------------------------------------------- build (prefix merged in)
__global__ __launch_bounds__(256)
void build_rows_all(const int* __restrict__ topk_e, int* __restrict__ counts,
                    int* __restrict__ offs, int* __restrict__ row_tok,
                    int* __restrict__ tok_row) {
    __shared__ int h[NEXP], hb[NEXP], lcnt[NEXP], loffs[NEXP];
    const int t = threadIdx.x;
    const int B = blockIdx.x;
    if (t < NEXP) { h[t] = 0; hb[t] = 0; lcnt[t] = 0; }
    __syncthreads();
    int cf[NEXP], cb[NEXP];
#pragma unroll
    for (int j = 0; j < NEXP; ++j) { cf[j] = 0; cb[j] = 0; }
    const int4* te4 = (const int4*)topk_e;
    const int gb = B * 128;  // int4 index boundary: g < gb <=> token < B*256
#pragma unroll
    for (int it = 0; it < 8; ++it) {
        int g = it * 256 + t;
        int4 v = te4[g];
        int before = (g < gb);
#pragma unroll
        for (int j = 0; j < NEXP; ++j) {
            int m = (v.x == j) + (v.y == j) + (v.z == j) + (v.w == j);
            cf[j] += m;
            cb[j] += before ? m : 0;
        }
    }
#pragma unroll
    for (int j = 0; j < NEXP; ++j) {
        if (cf[j]) atomicAdd(&h[j], cf[j]);
        if (cb[j]) atomicAdd(&hb[j], cb[j]);
    }
    __syncthreads();
    if (t == 0) {
        int s = 0;
        for (int e = 0; e < NEXP; ++e) { loffs[e] = s; s += h[e]; }
    }
    __syncthreads();
    const int tok = B * 256 + t;
    const int e0 = topk_e[tok * 2 + 0];
    const int e1 = topk_e[tok * 2 + 1];
    const int s0 = atomicAdd(&lcnt[e0], 1);
    const int s1 = atomicAdd(&lcnt[e1], 1);
    int r0 = loffs[e0] + hb[e0] + s0;
    row_tok[r0] = tok;
    tok_row[tok * 2 + 0] = r0;
    int r1 = loffs[e1] + hb[e1] + s1;
    row_tok[r1] = tok;
    tok_row[tok * 2 + 1] = r1;
    if (B == 0 && t < NEXP) {
        counts[t] = h[t];
        offs[t] = loffs[t];
        if (t == 0) offs[NEXP] = loffs[NEXP - 1] + h[NEXP - 1];
    }
}

// per-expert [R][C] fp32 -> [C][R] bf16, 64x64 LDS tiles. grid (C/64, R/64, E)
__global__ __launch_bounds__(256)
void transpose_f32_bf16(const float* __restrict__ src, u16* __restrict__ dst,
                        int R, int C) {
    __shared__ float tile[64][65];
    size_t eo = (size_t)blockIdx.z * R * C;
    const float* S = src + eo;
    u16* D = dst + eo;
    int r0 = blockIdx.y * 64, c0 = blockIdx.x * 64;
    int t = threadIdx.x;
    int rr = t >> 4;
    int cc = (t & 15) * 4;
#pragma unroll
    for (int it = 0; it < 4; ++it) {
        int r = rr + it * 16;
        float4 v = *(const float4*)(S + (size_t)(r0 + r) * C + (c0 + cc));
        tile[cc + 0][r] = v.x; tile[cc + 1][r] = v.y;
        tile[cc + 2][r] = v.z; tile[cc + 3][r] = v.w;
    }
    __syncthreads();
#pragma unroll
    for (int it = 0; it < 2; ++it) {
        int u = it * 256 + t;
        int c = u >> 3;
        int rv = (u & 7) * 8;
        uint4 o;
        o.x = pk2(tile[c][rv + 0], tile[c][rv + 1]);
        o.y = pk2(tile[c][rv + 2], tile[c][rv + 3]);
        o.z = pk2(tile[c][rv + 4], tile[c][rv + 5]);
        o.w = pk2(tile[c][rv + 6], tile[c][rv + 7]);
        *(uint4*)(D + (size_t)(c0 + c) * R + (r0 + rv)) = o;
    }
}

// ---------------------------------------------------------------- GEMM1 + SwiGLU
// 256-row tile, 8 waves (512 thr), 128 KiB double-buffered LDS, prefetch-1:
//   STAGE(next tile) -> COMPUTE(cur: 64 MFMA + 24 ds_read /wave) -> LGKM0 ->
//   WAITV0 -> BAR
// The round-5/7 pipelines failed because 128-tile phases (~16 MFMA) couldn't
// cover ~300-900cy load latency; this COMPUTE is ~600+cy/SIMD and does.
// Same sync skeleton as round 7 (correctness-verified); same chunk-XOR swizzle
// (conflicts=0, 16-row-aligned reads preserve the invariant); same XCD affinity.
// Output per block: 256m x 128n of act. Wave (wv&1)=m-half(128), (wv>>1)=n-
// quarter(32). acc = 8x2x2 floatx4 = 128 regs; ~210 VGPR total < 256 cap.
__global__ __launch_bounds__(512, 2)
void gemm1_fast(const u16* __restrict__ xb, const u16* __restrict__ w1b,
                u16* __restrict__ act, const int* __restrict__ row_tok,
                const int* __restrict__ counts, const int* __restrict__ offs) {
    const int bid = blockIdx.x;
    const int e = bid & 7;
    const int cnt = counts[e];
    const int nmb = (cnt + 255) >> 8;           // 256-row m-blocks
    const int j = bid >> 3;
    if (j >= nmb * 16) return;                  // 16 n-blocks of 128
    const int m0 = (j % nmb) * 256;             // m inner (fast)
    const int n0 = (j / nmb) * 128;             // n outer
    const int off = offs[e];

    // [buf][slab][row][32k]: 2*2*256*32 u16 = 64 KiB each
    __shared__ __align__(16) u16 As[2 * 2 * 256 * 32];
    __shared__ __align__(16) u16 Bs[2 * 2 * 256 * 32];  // r<128: g, r>=128: h

    const int t = threadIdx.x;
    const int lane = t & 63;
    const int wv = t >> 6;                      // 0..7
    const int quad = lane >> 4;
    const int rr = lane & 15;
    const int wm = (wv & 1) * 128;
    const int wn = (wv >> 1) * 32;

    // staging: 4 lanes cover one row's 32-k slab (64B); chunk order XOR-permuted
    const int scol = (((lane & 3) ^ ((lane >> 3) & 3)) * 8);
    // fragment read offset: logical chunk 'quad' lives at chunk quad^((rr>>1)&3)
    const int xq = (quad ^ ((rr >> 1) & 3)) * 8;
    const u16* arA[2];
    const u16* arB[2];
#pragma unroll
    for (int i = 0; i < 2; ++i) {
        int m = wv * 32 + i * 16 + ((lane >> 2) & 15);   // 0..255
        int r = m0 + m; if (r >= cnt) r = cnt - 1;
        arA[i] = xb + (size_t)row_tok[off + r] * DDIM + scol;
        size_t brow = (m < 128) ? ((size_t)e * 4096 + n0 + m)
                                : ((size_t)e * 4096 + 2048 + n0 + (m - 128));
        arB[i] = w1b + brow * DDIM + scol;
    }
    u16* dA[2] = { &As[(wv * 32) * 32], &As[(wv * 32 + 16) * 32] };
    u16* dB[2] = { &Bs[(wv * 32) * 32], &Bs[(wv * 32 + 16) * 32] };

    floatx4 accg[8][2] = {};
    floatx4 acch[8][2] = {};

#define G1_STAGE(b, ko)                                                         \
    { _Pragma("unroll") for (int s = 0; s < 2; ++s)                             \
      _Pragma("unroll") for (int i = 0; i < 2; ++i) {                           \
          gl_lds16(arA[i] + (ko) + s * 32, dA[i] + ((b) * 2 + s) * 8192);       \
          gl_lds16(arB[i] + (ko) + s * 32, dB[i] + ((b) * 2 + s) * 8192);       \
      } }

#define G1_COMPUTE(b)                                                           \
    { _Pragma("unroll") for (int s = 0; s < 2; ++s) {                           \
        short8 af[8], bg[2], bh[2];                                             \
        _Pragma("unroll") for (int mt = 0; mt < 8; ++mt)                        \
            af[mt] = *(const short8*)&As[((b) * 2 + s) * 8192 + (wm + mt * 16 + rr) * 32 + xq]; \
        _Pragma("unroll") for (int nt = 0; nt < 2; ++nt) {                      \
            bg[nt] = *(const short8*)&Bs[((b) * 2 + s) * 8192 + (wn + nt * 16 + rr) * 32 + xq]; \
            bh[nt] = *(const short8*)&Bs[((b) * 2 + s) * 8192 + (128 + wn + nt * 16 + rr) * 32 + xq]; } \
        _Pragma("unroll") for (int mt = 0; mt < 8; ++mt)                        \
        _Pragma("unroll") for (int nt = 0; nt < 2; ++nt) {                      \
            accg[mt][nt] = __builtin_amdgcn_mfma_f32_16x16x32_bf16(af[mt], bg[nt], accg[mt][nt], 0, 0, 0); \
            acch[mt][nt] = __builtin_amdgcn_mfma_f32_16x16x32_bf16(af[mt], bh[nt], acch[mt][nt], 0, 0, 0); } } }

    // 16 K-tiles of 64; one sync point per tile.
    G1_STAGE(0, 0);
    WAITV0; BAR; CFENCE;
    for (int p = 0; p < 7; ++p) {
        G1_STAGE(1, (2 * p + 1) * 64);
        G1_COMPUTE(0);
        LGKM0; WAITV0; BAR; CFENCE;
        G1_STAGE(0, (2 * p + 2) * 64);
        G1_COMPUTE(1);
        LGKM0; WAITV0; BAR; CFENCE;
    }
    G1_STAGE(1, 15 * 64);
    G1_COMPUTE(0);
    LGKM0; WAITV0; BAR; CFENCE;
    G1_COMPUTE(1);
#undef G1_STAGE
#undef G1_COMPUTE

#pragma unroll
    for (int mt = 0; mt < 8; ++mt)
#pragma unroll
        for (int nt = 0; nt < 2; ++nt)
#pragma unroll
            for (int rg = 0; rg < 4; ++rg) {
                int gm = m0 + wm + mt * 16 + quad * 4 + rg;
                if (gm < cnt) {
                    float g = accg[mt][nt][rg];
                    float h = acch[mt][nt][rg];
                    float s = g / (1.f + __expf(-g));
                    act[(size_t)(off + gm) * FDIM + (n0 + wn + nt * 16 + rr)] = f2bf(s * h);
                }
            }
}

// ---------------------------------------------------------------- GEMM2 (dense)
// act @ w2b[e] -> y[row][1024] fp32, plain stores; combine does gating.
// Unchanged (round-8 verified structure).
__global__ __launch_bounds__(256, 4)
void gemm2_fast(const u16* __restrict__ act, const u16* __restrict__ w2b,
                float* __restrict__ y, const int* __restrict__ counts,
                const int* __restrict__ offs) {
    const int bid = blockIdx.x;
    const int e = bid & 7;
    const int cnt = counts[e];
    const int nmb = (cnt + 127) >> 7;
    const int j = bid >> 3;
    if (j >= nmb * 8) return;                   // 8 n-blocks of 128
    const int m0 = (j % nmb) * 128;
    const int n0 = (j / nmb) * 128;
    const int off = offs[e];

    __shared__ __align__(16) u16 As[2 * 128 * 32];
    __shared__ __align__(16) u16 Bs[2 * 128 * 32];

    const int t = threadIdx.x;
    const int lane = t & 63;
    const int wv = t >> 6;
    const int quad = lane >> 4;
    const int rr = lane & 15;
    const int wm = (wv & 1) * 64;
    const int wn = (wv >> 1) * 64;

    const int scol = (((lane & 3) ^ ((lane >> 3) & 3)) * 8);
    const int xq = (quad ^ ((rr >> 1) & 3)) * 8;
    const u16* arA[2];
    const u16* arB[2];
#pragma unroll
    for (int i = 0; i < 2; ++i) {
        int m = wv * 32 + i * 16 + ((lane >> 2) & 15);
        int r = m0 + m; if (r >= cnt) r = cnt - 1;
        arA[i] = act + (size_t)(off + r) * FDIM + scol;
        arB[i] = w2b + ((size_t)e * 1024 + n0 + m) * FDIM + scol;
    }
    u16* dstA[2][2];
    u16* dstB[2][2];
#pragma unroll
    for (int s = 0; s < 2; ++s)
#pragma unroll
        for (int i = 0; i < 2; ++i) {
            dstA[s][i] = &As[(s * 128 + wv * 32 + i * 16) * 32];
            dstB[s][i] = &Bs[(s * 128 + wv * 32 + i * 16) * 32];
        }

    floatx4 acc[4][4] = {};

    for (int k0 = 0; k0 < FDIM; k0 += 64) {
        __syncthreads();
#pragma unroll
        for (int s = 0; s < 2; ++s)
#pragma unroll
            for (int i = 0; i < 2; ++i) {
                gl_lds16(arA[i] + k0 + s * 32, dstA[s][i]);
                gl_lds16(arB[i] + k0 + s * 32, dstB[s][i]);
            }
        __syncthreads();

#pragma unroll
        for (int s = 0; s < 2; ++s) {
            short8 af[4], bf[4];
#pragma unroll
            for (int mt = 0; mt < 4; ++mt)
                af[mt] = *(const short8*)&As[(s * 128 + wm + mt * 16 + rr) * 32 + xq];
#pragma unroll
            for (int nt = 0; nt < 4; ++nt)
                bf[nt] = *(const short8*)&Bs[(s * 128 + wn + nt * 16 + rr) * 32 + xq];
#pragma unroll
            for (int mt = 0; mt < 4; ++mt)
#pragma unroll
                for (int nt = 0; nt < 4; ++nt)
                    acc[mt][nt] = __builtin_amdgcn_mfma_f32_16x16x32_bf16(af[mt], bf[nt], acc[mt][nt], 0, 0, 0);
        }
    }
#pragma unroll
    for (int mt = 0; mt < 4; ++mt)
#pragma unroll
        for (int rg = 0; rg < 4; ++rg) {
            int gm = m0 + wm + mt * 16 + quad * 4 + rg;
            if (gm < cnt) {
                float* yrow = y + (size_t)(off + gm) * DDIM + n0 + wn;
#pragma unroll
                for (int nt = 0; nt < 4; ++nt)
                    yrow[nt * 16 + rr] = acc[mt][nt][rg];
            }
        }
}

// ---------------------------------------------------------------- combine
// out[tok] = w0 * y[row0(tok)] + w1 * y[row1(tok)]. Pure streaming, no atomics.
__global__ __launch_bounds__(256)
void combine_kernel(const float* __restrict__ y, const int* __restrict__ tok_row,
                    const float* __restrict__ topk_w, float* __restrict__ out) {
    const int tok = blockIdx.x;
    const int t = threadIdx.x;
    const int r0 = tok_row[tok * 2 + 0];
    const int r1 = tok_row[tok * 2 + 1];
    const float w0 = topk_w[tok * 2 + 0];
    const float w1 = topk_w[tok * 2 + 1];
    float4 a = *(const float4*)(y + (size_t)r0 * DDIM + t * 4);
    float4 b = *(const float4*)(y + (size_t)r1 * DDIM + t * 4);
    float4 o = { w0 * a.x + w1 * b.x, w0 * a.y + w1 * b.y,
                 w0 * a.z + w1 * b.z, w0 * a.w + w1 * b.w };
    *(float4*)(out + (size_t)tok * DDIM + t * 4) = o;
}

// ---------------------------------------------------------------- launch
extern "C" void kernel_launch(void* const* d_in, const int* in_sizes, int n_in,
                              void* d_out, int out_size, void* d_ws, size_t ws_size,
                              hipStream_t stream) {
    const float* x  = (const float*)d_in[0];  // [4096][1024]
    const float* rw = (const float*)d_in[1];  // [8][1024]
    const float* w1 = (const float*)d_in[2];  // [8][1024][4096] k-major
    const float* w2 = (const float*)d_in[3];  // [8][2048][1024] k-major
    float* out = (float*)d_out;               // [4096][1024]

    char* ws = (char*)d_ws;
    const size_t MB = 1ull << 20;
    int*   counts   = (int*)(ws);
    int*   offs     = (int*)(ws + 128);
    int*   topk_e   = (int*)(ws + 2048);            // 32 KiB
    float* topk_w   = (float*)(ws + 2048 + 32768);  // 32 KiB
    int*   row_tok  = (int*)(ws + 2048 + 65536);    // 32 KiB
    int*   tok_row  = (int*)(ws + 2048 + 98304);    // 32 KiB
    u16*   act      = (u16*)(ws + 1 * MB);    // 32 MiB
    u16*   xb       = (u16*)(ws + 33 * MB);   // 8 MiB
    u16*   w1b      = (u16*)(ws + 41 * MB);   // 64 MiB (alive through gemm1)
    u16*   w2b      = (u16*)(ws + 41 * MB);   // 32 MiB overlay (after gemm1)
    float* yb       = (float*)(ws + 73 * MB); // 32 MiB fp32

    router_kernel<<<dim3(NTOK / 4), 256, 0, stream>>>(x, rw, topk_e, topk_w, xb);
    build_rows_all<<<dim3(NTOK / 256), 256, 0, stream>>>(topk_e, counts, offs, row_tok, tok_row);
    transpose_f32_bf16<<<dim3(4096 / 64, 1024 / 64, NEXP), 256, 0, stream>>>(w1, w1b, 1024, 4096);
    // worst case per expert: 16 m-blocks (cnt<=4096) x 16 n-blocks -> 8*256 slots
    gemm1_fast<<<dim3(2048), 512, 0, stream>>>(xb, w1b, act, row_tok, counts, offs);
    transpose_f32_bf16<<<dim3(1024 / 64, 2048 / 64, NEXP), 256, 0, stream>>>(w2, w2b, 2048, 1024);
    gemm2_fast<<<dim3(2048), 256, 0, stream>>>(act, w2b, yb, counts, offs);
    combine_kernel<<<dim3(NTOK), 256, 0, stream>>>(yb, tok_row, topk_w, out);
    (void)in_sizes; (void)n_in; (void)ws_size;
}

// Round 12
// 431.305 us; speedup vs baseline: 1.0692x; 1.0692x over previous
//
#include <hip/hip_runtime.h>
#include <stdint.h>

typedef unsigned short u16;
typedef __attribute__((ext_vector_type(8))) short short8;   // 8 bf16 = 4 VGPRs
typedef __attribute__((ext_vector_type(4))) float floatx4;  // MFMA accumulator

#define NTOK 4096
#define DDIM 1024
#define FDIM 2048
#define NEXP 8

__device__ __forceinline__ u16 f2bf(float f) {
    union { float f; uint32_t u; } v; v.f = f;
    uint32_t r = v.u + 0x7fff + ((v.u >> 16) & 1);  // RNE
    return (u16)(r >> 16);
}
__device__ __forceinline__ uint32_t pk2(float a, float b) {
    return (uint32_t)f2bf(a) | ((uint32_t)f2bf(b) << 16);
}
// async global->LDS, 16B per lane; LDS dest is wave-uniform base + lane*16
__device__ __forceinline__ void gl_lds16(const u16* g, u16* l) {
    __builtin_amdgcn_global_load_lds(
        (const __attribute__((address_space(1))) uint32_t*)g,
        (__attribute__((address_space(3))) uint32_t*)l, 16, 0, 0);
}

// ---------------------------------------------------------------- router (+ x->bf16 fused)
__global__ __launch_bounds__(256)
void router_kernel(const float* __restrict__ x, const float* __restrict__ rw,
                   int* __restrict__ topk_e, float* __restrict__ topk_w,
                   u16* __restrict__ xb) {
    const int lane = threadIdx.x & 63;
    const int wv = threadIdx.x >> 6;
    const int tok = blockIdx.x * 4 + wv;
    const float* xr = x + (size_t)tok * DDIM;
    u16* xo = xb + (size_t)tok * DDIM;
    float acc[8];
#pragma unroll
    for (int e = 0; e < 8; ++e) acc[e] = 0.f;
#pragma unroll
    for (int it = 0; it < 4; ++it) {
        int d0 = (it * 64 + lane) * 4;
        float4 xv = *(const float4*)(xr + d0);
        uint2 o = { pk2(xv.x, xv.y), pk2(xv.z, xv.w) };
        *(uint2*)(xo + d0) = o;   // fused bf16 conversion
#pragma unroll
        for (int e = 0; e < 8; ++e) {
            float4 wv4 = *(const float4*)(rw + (size_t)e * DDIM + d0);
            acc[e] += xv.x * wv4.x + xv.y * wv4.y + xv.z * wv4.z + xv.w * wv4.w;
        }
    }
#pragma unroll
    for (int s = 32; s > 0; s >>= 1)
#pragma unroll
        for (int e = 0; e < 8; ++e) acc[e] += __shfl_down(acc[e], s);
    if (lane == 0) {
        int e0 = 0;
#pragma unroll
        for (int e = 1; e < 8; ++e) if (acc[e] > acc[e0]) e0 = e;
        int e1 = (e0 == 0) ? 1 : 0;
#pragma unroll
        for (int e = 0; e < 8; ++e) if (e != e0 && acc[e] > acc[e1]) e1 = e;
        float w0 = 1.f / (1.f + __expf(acc[e1] - acc[e0]));
        topk_e[tok * 2 + 0] = e0;
        topk_e[tok * 2 + 1] = e1;
        topk_w[tok * 2 + 0] = w0;
        topk_w[tok * 2 + 1] = 1.f - w0;
    }
}

// histogram (from topk_e) + prefix sums + cursor init. Single block.
__global__ __launch_bounds__(256)
void prefix_kernel(const int* __restrict__ topk_e, int* __restrict__ counts,
                   int* __restrict__ offs, int* __restrict__ cursors) {
    __shared__ int h[NEXP];
    const int t = threadIdx.x;
    if (t < NEXP) h[t] = 0;
    __syncthreads();
    int c[NEXP];
#pragma unroll
    for (int j = 0; j < NEXP; ++j) c[j] = 0;
    const int4* te4 = (const int4*)topk_e;
#pragma unroll
    for (int it = 0; it < 8; ++it) {
        int4 v = te4[it * 256 + t];
#pragma unroll
        for (int j = 0; j < NEXP; ++j)
            c[j] += (v.x == j) + (v.y == j) + (v.z == j) + (v.w == j);
    }
#pragma unroll
    for (int j = 0; j < NEXP; ++j)
        if (c[j]) atomicAdd(&h[j], c[j]);
    __syncthreads();
    if (t == 0) {
        int s = 0;
        for (int e = 0; e < NEXP; ++e) {
            counts[e] = h[e];
            offs[e] = s;
            s += h[e];
        }
        offs[NEXP] = s;
    }
    if (t < NEXP) cursors[t] = 0;
}

// block-aggregated slot assignment: LDS atomics for intra-block rank,
// ONE global atomic per expert per block. Records inverse map tok_row.
__global__ __launch_bounds__(256)
void build_rows(const int* __restrict__ topk_e, const int* __restrict__ offs,
                int* __restrict__ cursors, int* __restrict__ row_tok,
                int* __restrict__ tok_row) {
    __shared__ int lcnt[NEXP];
    __shared__ int lbase[NEXP];
    const int t = threadIdx.x;
    if (t < NEXP) lcnt[t] = 0;
    __syncthreads();
    const int tok = blockIdx.x * 256 + t;
    const int e0 = topk_e[tok * 2 + 0];
    const int e1 = topk_e[tok * 2 + 1];
    const int s0 = atomicAdd(&lcnt[e0], 1);
    const int s1 = atomicAdd(&lcnt[e1], 1);
    __syncthreads();
    if (t < NEXP) lbase[t] = lcnt[t] ? atomicAdd(&cursors[t], lcnt[t]) : 0;
    __syncthreads();
    int r0 = offs[e0] + lbase[e0] + s0;
    row_tok[r0] = tok;
    tok_row[tok * 2 + 0] = r0;
    int r1 = offs[e1] + lbase[e1] + s1;
    row_tok[r1] = tok;
    tok_row[tok * 2 + 1] = r1;
}

// per-expert [R][C] fp32 -> [C][R] bf16, 64x64 LDS tiles. grid (C/64, R/64, E)
__global__ __launch_bounds__(256)
void transpose_f32_bf16(const float* __restrict__ src, u16* __restrict__ dst,
                        int R, int C) {
    __shared__ float tile[64][65];
    size_t eo = (size_t)blockIdx.z * R * C;
    const float* S = src + eo;
    u16* D = dst + eo;
    int r0 = blockIdx.y * 64, c0 = blockIdx.x * 64;
    int t = threadIdx.x;
    int rr = t >> 4;
    int cc = (t & 15) * 4;
#pragma unroll
    for (int it = 0; it < 4; ++it) {
        int r = rr + it * 16;
        float4 v = *(const float4*)(S + (size_t)(r0 + r) * C + (c0 + cc));
        tile[cc + 0][r] = v.x; tile[cc + 1][r] = v.y;
        tile[cc + 2][r] = v.z; tile[cc + 3][r] = v.w;
    }
    __syncthreads();
#pragma unroll
    for (int it = 0; it < 2; ++it) {
        int u = it * 256 + t;
        int c = u >> 3;
        int rv = (u & 7) * 8;
        uint4 o;
        o.x = pk2(tile[c][rv + 0], tile[c][rv + 1]);
        o.y = pk2(tile[c][rv + 2], tile[c][rv + 3]);
        o.z = pk2(tile[c][rv + 4], tile[c][rv + 5]);
        o.w = pk2(tile[c][rv + 6], tile[c][rv + 7]);
        *(uint4*)(D + (size_t)(c0 + c) * R + (r0 + rv)) = o;
    }
}

// ---------------------------------------------------------------- GEMM1 + SwiGLU
// Round-6 proven 2-barrier schedule, NEW geometry: 256m x 64n tile, 8 waves
// (512 thr), 48 KiB LDS -> 2 blocks/CU = 16 waves/CU (was ~10). Per wave per
// K-step: stage 6 KiB for 32 MFMA (was 8 KiB) -> intensity 1.33x. Same
// chunk-XOR swizzle (all row bases 16-aligned -> invariant holds, conflicts 0),
// same XCD affinity (e = bid&7, m inner / n outer).
__global__ __launch_bounds__(512, 4)
void gemm1_fast(const u16* __restrict__ xb, const u16* __restrict__ w1b,
                u16* __restrict__ act, const int* __restrict__ row_tok,
                const int* __restrict__ counts, const int* __restrict__ offs) {
    const int bid = blockIdx.x;
    const int e = bid & 7;
    const int cnt = counts[e];
    const int nmb = (cnt + 255) >> 8;           // 256-row m-blocks
    const int j = bid >> 3;
    if (j >= nmb * 32) return;                  // 32 n-blocks of 64
    const int m0 = (j % nmb) * 256;             // m inner (fast)
    const int n0 = (j / nmb) * 64;              // n outer
    const int off = offs[e];

    __shared__ __align__(16) u16 As[2 * 256 * 32];  // [s][m][kk]   32 KiB
    __shared__ __align__(16) u16 Bs[2 * 128 * 32];  // [s][r][kk]   16 KiB; r<64 g, r>=64 h

    const int t = threadIdx.x;
    const int lane = t & 63;
    const int wv = t >> 6;                      // 0..7
    const int quad = lane >> 4;
    const int rr = lane & 15;
    const int wm = (wv >> 1) * 64;              // 4 m-groups of 64
    const int wn = (wv & 1) * 32;               // 2 n-groups of 32

    // staging: 4 lanes cover one row's 32-k slab (64B); chunk order XOR-permuted
    const int scol = (((lane & 3) ^ ((lane >> 3) & 3)) * 8);
    // fragment read offset: logical chunk 'quad' lives at chunk quad^((rr>>1)&3)
    const int xq = (quad ^ ((rr >> 1) & 3)) * 8;

    // A: wave stages rows wv*32 .. +31 (two 16-row groups); B: rows wv*16 .. +15
    const u16* arA[2];
    const u16* arB;
#pragma unroll
    for (int i = 0; i < 2; ++i) {
        int m = wv * 32 + i * 16 + ((lane >> 2) & 15);   // 0..255
        int r = m0 + m; if (r >= cnt) r = cnt - 1;
        arA[i] = xb + (size_t)row_tok[off + r] * DDIM + scol;
    }
    {
        int br = wv * 16 + ((lane >> 2) & 15);           // 0..127
        size_t brow = (br < 64) ? ((size_t)e * 4096 + n0 + br)
                                : ((size_t)e * 4096 + 2048 + n0 + (br - 64));
        arB = w1b + brow * DDIM + scol;
    }
    u16* dstA[2][2];
    u16* dstB[2];
#pragma unroll
    for (int s = 0; s < 2; ++s) {
#pragma unroll
        for (int i = 0; i < 2; ++i)
            dstA[s][i] = &As[(s * 256 + wv * 32 + i * 16) * 32];
        dstB[s] = &Bs[(s * 128 + wv * 16) * 32];
    }

    floatx4 accg[4][2] = {};
    floatx4 acch[4][2] = {};

    for (int k0 = 0; k0 < DDIM; k0 += 64) {
        __syncthreads();
#pragma unroll
        for (int s = 0; s < 2; ++s) {
#pragma unroll
            for (int i = 0; i < 2; ++i)
                gl_lds16(arA[i] + k0 + s * 32, dstA[s][i]);
            gl_lds16(arB + k0 + s * 32, dstB[s]);
        }
        __syncthreads();

#pragma unroll
        for (int s = 0; s < 2; ++s) {
            short8 af[4], bg[2], bh[2];
#pragma unroll
            for (int mt = 0; mt < 4; ++mt)
                af[mt] = *(const short8*)&As[(s * 256 + wm + mt * 16 + rr) * 32 + xq];
#pragma unroll
            for (int nt = 0; nt < 2; ++nt) {
                bg[nt] = *(const short8*)&Bs[(s * 128 + wn + nt * 16 + rr) * 32 + xq];
                bh[nt] = *(const short8*)&Bs[(s * 128 + 64 + wn + nt * 16 + rr) * 32 + xq];
            }
#pragma unroll
            for (int mt = 0; mt < 4; ++mt)
#pragma unroll
                for (int nt = 0; nt < 2; ++nt) {
                    accg[mt][nt] = __builtin_amdgcn_mfma_f32_16x16x32_bf16(af[mt], bg[nt], accg[mt][nt], 0, 0, 0);
                    acch[mt][nt] = __builtin_amdgcn_mfma_f32_16x16x32_bf16(af[mt], bh[nt], acch[mt][nt], 0, 0, 0);
                }
        }
    }
#pragma unroll
    for (int mt = 0; mt < 4; ++mt)
#pragma unroll
        for (int nt = 0; nt < 2; ++nt)
#pragma unroll
            for (int rg = 0; rg < 4; ++rg) {
                int gm = m0 + wm + mt * 16 + quad * 4 + rg;
                if (gm < cnt) {
                    float g = accg[mt][nt][rg];
                    float h = acch[mt][nt][rg];
                    float s = g / (1.f + __expf(-g));
                    act[(size_t)(off + gm) * FDIM + (n0 + wn + nt * 16 + rr)] = f2bf(s * h);
                }
            }
}

// ---------------------------------------------------------------- GEMM2 (dense)
// act @ w2b[e] -> y[row][1024] fp32, plain stores; combine does gating.
// Round-8 verified structure, unchanged.
__global__ __launch_bounds__(256, 2)
void gemm2_fast(const u16* __restrict__ act, const u16* __restrict__ w2b,
                float* __restrict__ y, const int* __restrict__ counts,
                const int* __restrict__ offs) {
    const int bid = blockIdx.x;
    const int e = bid & 7;
    const int cnt = counts[e];
    const int nmb = (cnt + 127) >> 7;
    const int j = bid >> 3;
    if (j >= nmb * 8) return;                   // 8 n-blocks of 128
    const int m0 = (j % nmb) * 128;
    const int n0 = (j / nmb) * 128;
    const int off = offs[e];

    __shared__ __align__(16) u16 As[2 * 128 * 32];
    __shared__ __align__(16) u16 Bs[2 * 128 * 32];

    const int t = threadIdx.x;
    const int lane = t & 63;
    const int wv = t >> 6;
    const int quad = lane >> 4;
    const int rr = lane & 15;
    const int wm = (wv & 1) * 64;
    const int wn = (wv >> 1) * 64;

    const int scol = (((lane & 3) ^ ((lane >> 3) & 3)) * 8);
    const int xq = (quad ^ ((rr >> 1) & 3)) * 8;
    const u16* arA[2];
    const u16* arB[2];
#pragma unroll
    for (int i = 0; i < 2; ++i) {
        int m = wv * 32 + i * 16 + ((lane >> 2) & 15);
        int r = m0 + m; if (r >= cnt) r = cnt - 1;
        arA[i] = act + (size_t)(off + r) * FDIM + scol;
        arB[i] = w2b + ((size_t)e * 1024 + n0 + m) * FDIM + scol;
    }
    u16* dstA[2][2];
    u16* dstB[2][2];
#pragma unroll
    for (int s = 0; s < 2; ++s)
#pragma unroll
        for (int i = 0; i < 2; ++i) {
            dstA[s][i] = &As[(s * 128 + wv * 32 + i * 16) * 32];
            dstB[s][i] = &Bs[(s * 128 + wv * 32 + i * 16) * 32];
        }

    floatx4 acc[4][4] = {};

    for (int k0 = 0; k0 < FDIM; k0 += 64) {
        __syncthreads();
#pragma unroll
        for (int s = 0; s < 2; ++s)
#pragma unroll
            for (int i = 0; i < 2; ++i) {
                gl_lds16(arA[i] + k0 + s * 32, dstA[s][i]);
                gl_lds16(arB[i] + k0 + s * 32, dstB[s][i]);
            }
        __syncthreads();

#pragma unroll
        for (int s = 0; s < 2; ++s) {
            short8 af[4], bf[4];
#pragma unroll
            for (int mt = 0; mt < 4; ++mt)
                af[mt] = *(const short8*)&As[(s * 128 + wm + mt * 16 + rr) * 32 + xq];
#pragma unroll
            for (int nt = 0; nt < 4; ++nt)
                bf[nt] = *(const short8*)&Bs[(s * 128 + wn + nt * 16 + rr) * 32 + xq];
#pragma unroll
            for (int mt = 0; mt < 4; ++mt)
#pragma unroll
                for (int nt = 0; nt < 4; ++nt)
                    acc[mt][nt] = __builtin_amdgcn_mfma_f32_16x16x32_bf16(af[mt], bf[nt], acc[mt][nt], 0, 0, 0);
        }
    }
#pragma unroll
    for (int mt = 0; mt < 4; ++mt)
#pragma unroll
        for (int rg = 0; rg < 4; ++rg) {
            int gm = m0 + wm + mt * 16 + quad * 4 + rg;
            if (gm < cnt) {
                float* yrow = y + (size_t)(off + gm) * DDIM + n0 + wn;
#pragma unroll
                for (int nt = 0; nt < 4; ++nt)
                    yrow[nt * 16 + rr] = acc[mt][nt][rg];
            }
        }
}

// ---------------------------------------------------------------- combine
// out[tok] = w0 * y[row0(tok)] + w1 * y[row1(tok)]. Pure streaming, no atomics.
__global__ __launch_bounds__(256)
void combine_kernel(const float* __restrict__ y, const int* __restrict__ tok_row,
                    const float* __restrict__ topk_w, float* __restrict__ out) {
    const int tok = blockIdx.x;
    const int t = threadIdx.x;
    const int r0 = tok_row[tok * 2 + 0];
    const int r1 = tok_row[tok * 2 + 1];
    const float w0 = topk_w[tok * 2 + 0];
    const float w1 = topk_w[tok * 2 + 1];
    float4 a = *(const float4*)(y + (size_t)r0 * DDIM + t * 4);
    float4 b = *(const float4*)(y + (size_t)r1 * DDIM + t * 4);
    float4 o = { w0 * a.x + w1 * b.x, w0 * a.y + w1 * b.y,
                 w0 * a.z + w1 * b.z, w0 * a.w + w1 * b.w };
    *(float4*)(out + (size_t)tok * DDIM + t * 4) = o;
}

// ---------------------------------------------------------------- launch
extern "C" void kernel_launch(void* const* d_in, const int* in_sizes, int n_in,
                              void* d_out, int out_size, void* d_ws, size_t ws_size,
                              hipStream_t stream) {
    const float* x  = (const float*)d_in[0];  // [4096][1024]
    const float* rw = (const float*)d_in[1];  // [8][1024]
    const float* w1 = (const float*)d_in[2];  // [8][1024][4096] k-major
    const float* w2 = (const float*)d_in[3];  // [8][2048][1024] k-major
    float* out = (float*)d_out;               // [4096][1024]

    char* ws = (char*)d_ws;
    const size_t MB = 1ull << 20;
    int*   counts   = (int*)(ws);
    int*   cursors  = (int*)(ws + 64);
    int*   offs     = (int*)(ws + 128);
    int*   topk_e   = (int*)(ws + 2048);            // 32 KiB
    float* topk_w   = (float*)(ws + 2048 + 32768);  // 32 KiB
    int*   row_tok  = (int*)(ws + 2048 + 65536);    // 32 KiB
    int*   tok_row  = (int*)(ws + 2048 + 98304);    // 32 KiB
    u16*   act      = (u16*)(ws + 1 * MB);    // 32 MiB
    u16*   xb       = (u16*)(ws + 33 * MB);   // 8 MiB
    u16*   w1b      = (u16*)(ws + 41 * MB);   // 64 MiB (alive through gemm1)
    u16*   w2b      = (u16*)(ws + 41 * MB);   // 32 MiB overlay (after gemm1)
    float* yb       = (float*)(ws + 73 * MB); // 32 MiB fp32

    router_kernel<<<dim3(NTOK / 4), 256, 0, stream>>>(x, rw, topk_e, topk_w, xb);
    prefix_kernel<<<1, 256, 0, stream>>>(topk_e, counts, offs, cursors);
    build_rows<<<dim3(NTOK / 256), 256, 0, stream>>>(topk_e, offs, cursors, row_tok, tok_row);
    transpose_f32_bf16<<<dim3(4096 / 64, 1024 / 64, NEXP), 256, 0, stream>>>(w1, w1b, 1024, 4096);
    // worst case per expert: 16 m-blocks (cnt<=4096) x 32 n-blocks -> 8*512 slots
    gemm1_fast<<<dim3(4096), 512, 0, stream>>>(xb, w1b, act, row_tok, counts, offs);
    transpose_f32_bf16<<<dim3(1024 / 64, 2048 / 64, NEXP), 256, 0, stream>>>(w2, w2b, 2048, 1024);
    gemm2_fast<<<dim3(2048), 256, 0, stream>>>(act, w2b, yb, counts, offs);
    combine_kernel<<<dim3(NTOK), 256, 0, stream>>>(yb, tok_row, topk_w, out);
    (void)in_sizes; (void)n_in; (void)ws_size;
}